// Round 2
// baseline (92.926 us; speedup 1.0000x reference)
//
#include <hip/hip_runtime.h>
#include <math.h>

#define KG 128

// 2D Gaussian splatting forward — LITERAL per-step recurrence to match the
// reference's eps semantics:
//   w  = alpha_k * exp(expo)
//   na = pa + w*(1-pa)
//   pc = clip((pc*pa + col*w*(1-pa)) / (na + 1e-8), 0, 255)
//   pa = clip(na, 0, 1)
// Params staged in LDS once per block (broadcast reads, conflict-free).
__global__ __launch_bounds__(256) void splat_fwd(
    const float* __restrict__ pos,     // [N,2]
    const float* __restrict__ mu,      // [K,2]
    const float* __restrict__ alpha,   // [K]
    const float* __restrict__ color,   // [K,3]
    const float* __restrict__ scales,  // [K,2]
    const float* __restrict__ thetas,  // [K]
    float* __restrict__ out,           // [N,4]
    int n)
{
    __shared__ float4 sP0[KG];  // mux, muy, A', B'  (A',B',C' = -0.5*log2e * sigma_inv coeffs)
    __shared__ float4 sP1[KG];  // C', alpha, col_r, col_g
    __shared__ float  sP2[KG];  // col_b

    const int tid = threadIdx.x;
    if (tid < KG) {
        const int k = tid;
        const float mx = mu[2 * k];
        const float my = mu[2 * k + 1];
        const float al = fminf(fmaxf(alpha[k], 0.0f), 1.0f);
        const float cr = fminf(fmaxf(color[3 * k + 0], 0.0f), 255.0f);
        const float cg = fminf(fmaxf(color[3 * k + 1], 0.0f), 255.0f);
        const float cb = fminf(fmaxf(color[3 * k + 2], 0.0f), 255.0f);
        const float sx = fmaxf(scales[2 * k + 0], 0.1f);
        const float sy = fmaxf(scales[2 * k + 1], 0.1f);
        const float th = thetas[k];
        const float c = cosf(th);
        const float s = sinf(th);
        const float i0 = 1.0f / (sx * sx);
        const float i1 = 1.0f / (sy * sy);
        // sigma_inv = R diag(i0,i1) R^T = [[a, b], [b, cc]]
        const float a  = c * c * i0 + s * s * i1;
        const float b  = c * s * (i0 - i1);
        const float cc = s * s * i0 + c * c * i1;
        // expo = -0.5*(a dx^2 + 2b dx dy + cc dy^2); fold -0.5*log2(e) so the
        // exponent feeds exp2 (v_exp_f32) directly.
        const float f = -0.5f * 1.4426950408889634f;
        sP0[k] = make_float4(mx, my, a * f, 2.0f * b * f);
        sP1[k] = make_float4(cc * f, al, cr, cg);
        sP2[k] = cb;
    }
    __syncthreads();

    const int i = blockIdx.x * blockDim.x + tid;
    if (i >= n) return;

    const float2 p = reinterpret_cast<const float2*>(pos)[i];

    float pa = 0.0f;
    float pcr = 0.0f, pcg = 0.0f, pcb = 0.0f;

#pragma unroll 4
    for (int k = 0; k < KG; ++k) {
        const float4 q0 = sP0[k];
        const float4 q1 = sP1[k];
        const float  q2 = sP2[k];
        const float dx = p.x - q0.x;
        const float dy = p.y - q0.y;
        const float e = q0.z * (dx * dx) + q0.w * (dx * dy) + q1.x * (dy * dy);
        const float w = q1.y * __builtin_amdgcn_exp2f(e);   // alpha_k

        const float omp = 1.0f - pa;            // (1 - pa)
        const float t1  = w * omp;              // alpha_k * (1 - pa)
        const float na  = pa + t1;              // new_alpha
        const float r   = __builtin_amdgcn_rcpf(na + 1e-8f);

        pcr = fminf(fmaxf((pcr * pa + q1.z * t1) * r, 0.0f), 255.0f);
        pcg = fminf(fmaxf((pcg * pa + q1.w * t1) * r, 0.0f), 255.0f);
        pcb = fminf(fmaxf((pcb * pa + q2  * t1) * r, 0.0f), 255.0f);
        pa  = fminf(na, 1.0f);                  // na >= 0 always
    }

    float4 o;
    o.x = pcr;
    o.y = pcg;
    o.z = pcb;
    o.w = pa * 255.0f;
    reinterpret_cast<float4*>(out)[i] = o;
}

extern "C" void kernel_launch(void* const* d_in, const int* in_sizes, int n_in,
                              void* d_out, int out_size, void* d_ws, size_t ws_size,
                              hipStream_t stream) {
    const float* pos    = (const float*)d_in[0];
    const float* mu     = (const float*)d_in[1];
    const float* alpha  = (const float*)d_in[2];
    const float* color  = (const float*)d_in[3];
    const float* scales = (const float*)d_in[4];
    const float* thetas = (const float*)d_in[5];
    float* out = (float*)d_out;

    const int n = in_sizes[0] / 2;   // N pixels
    const int block = 256;
    const int grid = (n + block - 1) / block;
    hipLaunchKernelGGL(splat_fwd, dim3(grid), dim3(block), 0, stream,
                       pos, mu, alpha, color, scales, thetas, out, n);
}

// Round 4
// 81.553 us; speedup vs baseline: 1.1395x; 1.1395x over previous
//
#include <hip/hip_runtime.h>
#include <math.h>

#define KG 128

typedef float f32x2 __attribute__((ext_vector_type(2)));

// 2D Gaussian splatting forward. Literal eps-semantics recurrence, but
// tracking the color NUMERATOR instead of the divided color:
//   pc_k = num_k / (na_k + eps)  (never materialized in-loop)
//   num_k = num_{k-1} * (r_{k-1} * pa_{k-1}) + col * t1_k
// Per-step clips are mathematically inert (num <= 255*na => pc < 255).
// Two pixels per thread as float2 -> compiler packs to v_pk_fma_f32 etc.
__global__ __launch_bounds__(256) void splat_fwd(
    const float* __restrict__ pos,     // [N,2]
    const float* __restrict__ mu,      // [K,2]
    const float* __restrict__ alpha,   // [K]
    const float* __restrict__ color,   // [K,3]
    const float* __restrict__ scales,  // [K,2]
    const float* __restrict__ thetas,  // [K]
    float* __restrict__ out,           // [N,4]
    int nPairs)
{
    __shared__ float4 sP0[KG];  // mux, muy, A', B'  (A',B',C' = -0.5*log2e * sigma_inv)
    __shared__ float4 sP1[KG];  // C', alpha, col_r, col_g
    __shared__ float  sP2[KG];  // col_b

    const int tid = threadIdx.x;
    if (tid < KG) {
        const int k = tid;
        const float mx = mu[2 * k];
        const float my = mu[2 * k + 1];
        const float al = fminf(fmaxf(alpha[k], 0.0f), 1.0f);
        const float cr = fminf(fmaxf(color[3 * k + 0], 0.0f), 255.0f);
        const float cg = fminf(fmaxf(color[3 * k + 1], 0.0f), 255.0f);
        const float cb = fminf(fmaxf(color[3 * k + 2], 0.0f), 255.0f);
        const float sx = fmaxf(scales[2 * k + 0], 0.1f);
        const float sy = fmaxf(scales[2 * k + 1], 0.1f);
        const float th = thetas[k];
        const float c = cosf(th);
        const float s = sinf(th);
        const float i0 = 1.0f / (sx * sx);
        const float i1 = 1.0f / (sy * sy);
        const float a  = c * c * i0 + s * s * i1;
        const float b  = c * s * (i0 - i1);
        const float cc = s * s * i0 + c * c * i1;
        const float f = -0.5f * 1.4426950408889634f;   // fold -0.5*log2e -> exp2
        sP0[k] = make_float4(mx, my, a * f, 2.0f * b * f);
        sP1[k] = make_float4(cc * f, al, cr, cg);
        sP2[k] = cb;
    }
    __syncthreads();

    const int t = blockIdx.x * blockDim.x + tid;   // pixel-pair index
    if (t >= nPairs) return;

    const float4 pp = reinterpret_cast<const float4*>(pos)[t]; // x0,y0,x1,y1
    const f32x2 px = { pp.x, pp.z };
    const f32x2 py = { pp.y, pp.w };

    f32x2 pa    = { 0.0f, 0.0f };
    f32x2 rprev = { 0.0f, 0.0f };   // irrelevant at k=0 since pa=0
    f32x2 numr  = { 0.0f, 0.0f };
    f32x2 numg  = { 0.0f, 0.0f };
    f32x2 numb  = { 0.0f, 0.0f };

#pragma unroll 4
    for (int k = 0; k < KG; ++k) {
        const float4 q0 = sP0[k];
        const float4 q1 = sP1[k];
        const float  q2 = sP2[k];

        const f32x2 dx = px - q0.x;
        const f32x2 dy = py - q0.y;
        const f32x2 u  = q0.z * dx + q0.w * dy;        // A*dx + B*dy (pk fma)
        const f32x2 e  = dx * u + (q1.x * dy) * dy;    // + C*dy^2

        f32x2 E;
        E.x = __builtin_amdgcn_exp2f(e.x);
        E.y = __builtin_amdgcn_exp2f(e.y);

        const f32x2 w   = q1.y * E;        // alpha_k
        const f32x2 omp = 1.0f - pa;
        const f32x2 t1  = w * omp;
        const f32x2 na  = pa + t1;
        const f32x2 nae = na + 1e-8f;

        f32x2 r;
        r.x = __builtin_amdgcn_rcpf(nae.x);
        r.y = __builtin_amdgcn_rcpf(nae.y);

        const f32x2 h = rprev * pa;        // pc_{k-1} scale: num*h == pc*pa
        numr = numr * h + q1.z * t1;
        numg = numg * h + q1.w * t1;
        numb = numb * h + q2  * t1;

        pa.x = fminf(na.x, 1.0f);
        pa.y = fminf(na.y, 1.0f);
        rprev = r;
    }

    const f32x2 pcr = numr * rprev;
    const f32x2 pcg = numg * rprev;
    const f32x2 pcb = numb * rprev;

    float4 o0, o1;
    o0.x = fminf(fmaxf(pcr.x, 0.0f), 255.0f);
    o0.y = fminf(fmaxf(pcg.x, 0.0f), 255.0f);
    o0.z = fminf(fmaxf(pcb.x, 0.0f), 255.0f);
    o0.w = pa.x * 255.0f;
    o1.x = fminf(fmaxf(pcr.y, 0.0f), 255.0f);
    o1.y = fminf(fmaxf(pcg.y, 0.0f), 255.0f);
    o1.z = fminf(fmaxf(pcb.y, 0.0f), 255.0f);
    o1.w = pa.y * 255.0f;

    float4* o = reinterpret_cast<float4*>(out);
    o[2 * t]     = o0;
    o[2 * t + 1] = o1;
}

extern "C" void kernel_launch(void* const* d_in, const int* in_sizes, int n_in,
                              void* d_out, int out_size, void* d_ws, size_t ws_size,
                              hipStream_t stream) {
    const float* pos    = (const float*)d_in[0];
    const float* mu     = (const float*)d_in[1];
    const float* alpha  = (const float*)d_in[2];
    const float* color  = (const float*)d_in[3];
    const float* scales = (const float*)d_in[4];
    const float* thetas = (const float*)d_in[5];
    float* out = (float*)d_out;

    const int n = in_sizes[0] / 2;       // N pixels
    const int nPairs = n / 2;            // N is even (512*512)
    const int block = 256;
    const int grid = (nPairs + block - 1) / block;
    hipLaunchKernelGGL(splat_fwd, dim3(grid), dim3(block), 0, stream,
                       pos, mu, alpha, color, scales, thetas, out, nPairs);
}